// Round 7
// baseline (277.177 us; speedup 1.0000x reference)
//
#include <hip/hip_runtime.h>
#include <math.h>

// Problem constants (fixed by reference setup_inputs)
#define NN 8192
#define SS 32
#define DD 32
#define KK 1024
#define OUT_ELEMS ((size_t)NN * SS * DD)   // 8388608; loss scalar at out[OUT_ELEMS]

// loss = S * (1 + BETA) * sum_sq / (N*S*D)
#define LOSS_SCALE (32.0f * 1.001f / 8388608.0f)

typedef _Float16 half8 __attribute__((ext_vector_type(8)));
typedef float   floatx4 __attribute__((ext_vector_type(4)));

#define KSPLIT   4                    // k-range blocks per (n-tile, s)
#define KLOC     (KK / KSPLIT)        // 256 codewords per block
#define CH_TILES 4                    // k-tiles of 16 per chunk
#define CHUNK_K  (CH_TILES * 16)      // 64 codewords per chunk
#define NCHUNK   (KLOC / CHUNK_K)     // 4 chunks
#define RG 4                          // 16-row groups per wave -> 64 rows/wave

// Sortable encoding: min over packed u64 == (min score, then min k).
__device__ __forceinline__ unsigned long long pack_score(float v, int k) {
    unsigned int b = __float_as_uint(v);
    b = (b & 0x80000000u) ? ~b : (b | 0x80000000u);
    return ((unsigned long long)b << 32) | (unsigned int)k;
}

// Main: block = 4 waves, 256 n-rows x 256 codewords for one s.
// Grid 4096 = 16 blocks/CU available -> 8 waves/SIMD resident (VGPR<=64 goal).
// Per 64-k chunk: cooperative fp32->f16 hi/lo split into LDS fragment order
// (conflict-free b128), ||W||^2 alongside; then 4 tiles x RG x 3 split-MFMAs
// + per-slot argmin. Winners -> packed u64 atomicMin in ws.
__global__ __launch_bounds__(256, 4) void vq_main(const float* __restrict__ z,
                                                  const float* __restrict__ W,
                                                  unsigned long long* __restrict__ ws) {
    __shared__ _Float16 bufH[2][CH_TILES][64][8];   // 8 KB
    __shared__ _Float16 bufL[2][CH_TILES][64][8];   // 8 KB
    __shared__ float    w2b[2][CHUNK_K];            // 512 B

    const int s    = blockIdx.x & (SS - 1);
    const int ks   = (blockIdx.x >> 5) & (KSPLIT - 1);
    const int n0b  = (blockIdx.x >> 7) * 256;
    const int tid  = threadIdx.x;
    const int wv   = tid >> 6;
    const int lane = tid & 63;
    const int col  = lane & 15;
    const int quad = lane >> 4;

    const float* __restrict__ Ws = W + ((size_t)s * KK + ks * KLOC) * DD;
    const int n0w = n0b + wv * 64;

    // ---- A-fragments: (-2*z) split into f16 hi/lo. A[m=col][d=quad*8+j]. ----
    half8 zh[RG], zl[RG];
    #pragma unroll
    for (int rg = 0; rg < RG; ++rg) {
        const float* zp = z + (size_t)(n0w + rg * 16 + col) * (SS * DD) + s * DD + quad * 8;
        const float4 va = ((const float4*)zp)[0];
        const float4 vb = ((const float4*)zp)[1];
        const float src[8] = {va.x, va.y, va.z, va.w, vb.x, vb.y, vb.z, vb.w};
        #pragma unroll
        for (int j = 0; j < 8; ++j) {
            const float v = -2.0f * src[j];
            const _Float16 h = (_Float16)v;
            zh[rg][j] = h;
            zl[rg][j] = (_Float16)(v - (float)h);
        }
    }

    // Staging source: thread covers k-row (chunk*64 + wv*16 + col), d=quad*8..+7.
    const float* __restrict__ stg = Ws + ((size_t)(wv * 16 + col)) * DD + quad * 8;

    floatx4 best[RG];
    int bi[RG][4];
    #pragma unroll
    for (int rg = 0; rg < RG; ++rg) {
        best[rg] = (floatx4){INFINITY, INFINITY, INFINITY, INFINITY};
        bi[rg][0] = bi[rg][1] = bi[rg][2] = bi[rg][3] = 0;
    }

    // ---- prologue: stage chunk 0 ----
    float4 pa = ((const float4*)stg)[0];
    float4 pb = ((const float4*)stg)[1];
    {
        const float src[8] = {pa.x, pa.y, pa.z, pa.w, pb.x, pb.y, pb.z, pb.w};
        half8 h8, l8; float ps = 0.0f;
        #pragma unroll
        for (int j = 0; j < 8; ++j) {
            const float v = src[j];
            ps = fmaf(v, v, ps);
            const _Float16 h = (_Float16)v;
            h8[j] = h;
            l8[j] = (_Float16)(v - (float)h);
        }
        ps += __shfl_xor(ps, 16, 64);
        ps += __shfl_xor(ps, 32, 64);
        *(half8*)&bufH[0][wv][lane][0] = h8;
        *(half8*)&bufL[0][wv][lane][0] = l8;
        if (quad == 0) w2b[0][wv * 16 + col] = ps;
    }
    __syncthreads();

    // ---- main K loop, double-buffered ----
    for (int c = 0; c < NCHUNK; ++c) {
        const int b = c & 1;
        if (c + 1 < NCHUNK) {   // issue next chunk's global loads early
            const float* nsrc = stg + (size_t)(c + 1) * CHUNK_K * DD;
            pa = ((const float4*)nsrc)[0];
            pb = ((const float4*)nsrc)[1];
        }

        #pragma unroll
        for (int tt = 0; tt < CH_TILES; ++tt) {
            const half8 bh = *(const half8*)&bufH[b][tt][lane][0];
            const half8 bl = *(const half8*)&bufL[b][tt][lane][0];
            const float wv2 = w2b[b][tt * 16 + col];
            const floatx4 c0 = {wv2, wv2, wv2, wv2};
            const int tk = c * CH_TILES + tt;
            #pragma unroll
            for (int rg = 0; rg < RG; ++rg) {
                floatx4 acc = __builtin_amdgcn_mfma_f32_16x16x32_f16(zh[rg], bh, c0, 0, 0, 0);
                acc = __builtin_amdgcn_mfma_f32_16x16x32_f16(zl[rg], bh, acc, 0, 0, 0);
                acc = __builtin_amdgcn_mfma_f32_16x16x32_f16(zh[rg], bl, acc, 0, 0, 0);
                #pragma unroll
                for (int i = 0; i < 4; ++i) {
                    if (acc[i] < best[rg][i]) { best[rg][i] = acc[i]; bi[rg][i] = tk; }  // strict <
                }
            }
        }

        if (c + 1 < NCHUNK) {
            const float src[8] = {pa.x, pa.y, pa.z, pa.w, pb.x, pb.y, pb.z, pb.w};
            half8 h8, l8; float ps = 0.0f;
            #pragma unroll
            for (int j = 0; j < 8; ++j) {
                const float v = src[j];
                ps = fmaf(v, v, ps);
                const _Float16 h = (_Float16)v;
                h8[j] = h;
                l8[j] = (_Float16)(v - (float)h);
            }
            ps += __shfl_xor(ps, 16, 64);
            ps += __shfl_xor(ps, 32, 64);
            const int nb = (c + 1) & 1;
            *(half8*)&bufH[nb][wv][lane][0] = h8;
            *(half8*)&bufL[nb][wv][lane][0] = l8;
            if (quad == 0) w2b[nb][wv * 16 + col] = ps;
            __syncthreads();
        }
    }

    // ---- cross-lane argmin over 16 k-cols; merge across blocks via atomicMin ----
    const int kbase = ks * KLOC;
    #pragma unroll
    for (int rg = 0; rg < RG; ++rg) {
        #pragma unroll
        for (int i = 0; i < 4; ++i) {
            float v = best[rg][i];
            int   k = kbase + bi[rg][i] * 16 + col;
            #pragma unroll
            for (int m = 1; m < 16; m <<= 1) {
                const float vo = __shfl_xor(v, m, 64);
                const int   ko = __shfl_xor(k, m, 64);
                if (vo < v || (vo == v && ko < k)) { v = vo; k = ko; }
            }
            if (col == 0) {
                const int n = n0w + rg * 16 + quad * 4 + i;   // C-layout row
                atomicMin(&ws[(size_t)n * SS + s], pack_score(v, k));
            }
        }
    }
}

// Epilogue: 2 lanes per n-row (16 floats each). Reads winner k from ws,
// gathers fp32 W (L2-resident), writes zq, accumulates loss.
__global__ __launch_bounds__(256) void vq_epi(const float* __restrict__ z,
                                              const float* __restrict__ W,
                                              const unsigned long long* __restrict__ ws,
                                              float* __restrict__ out) {
    const int s    = blockIdx.x & (SS - 1);
    const int n0b  = (blockIdx.x >> 5) * 128;
    const int tid  = threadIdx.x;
    const int wv   = tid >> 6;
    const int lane = tid & 63;

    const int r  = lane & 31;                 // row within this wave's 32
    const int dh = (lane >> 5) * 16;          // d-half
    const int n  = n0b + wv * 32 + r;

    const int krow = (int)(ws[(size_t)n * SS + s] & 0xFFFFFFFFu);
    const float* wsrc = W + ((size_t)s * KK + krow) * DD + dh;
    const size_t zoff = (size_t)n * (SS * DD) + s * DD + dh;
    const float* zsrc = z + zoff;
    float* od = out + zoff;
    float sq = 0.0f;
    #pragma unroll
    for (int cc = 0; cc < 4; ++cc) {
        const float4 wq = ((const float4*)wsrc)[cc];
        const float4 zv = ((const float4*)zsrc)[cc];
        const float d0 = wq.x - zv.x, d1 = wq.y - zv.y;
        const float d2 = wq.z - zv.z, d3 = wq.w - zv.w;
        sq = fmaf(d0, d0, sq); sq = fmaf(d1, d1, sq);
        sq = fmaf(d2, d2, sq); sq = fmaf(d3, d3, sq);
        ((float4*)od)[cc] = wq;
    }
    #pragma unroll
    for (int off = 32; off > 0; off >>= 1) sq += __shfl_down(sq, off, 64);
    if (lane == 0) atomicAdd(out + OUT_ELEMS, sq * LOSS_SCALE);
}

extern "C" void kernel_launch(void* const* d_in, const int* in_sizes, int n_in,
                              void* d_out, int out_size, void* d_ws, size_t ws_size,
                              hipStream_t stream) {
    const float* z = (const float*)d_in[0];   // (8192, 1024) fp32
    const float* W = (const float*)d_in[1];   // (32, 1024, 32) fp32
    float* out = (float*)d_out;               // 8388608 zq_st + 1 loss
    unsigned long long* ws = (unsigned long long*)d_ws;   // N*S packed winners (2 MB)

    // 0xFF = +inf sentinel for packed scores (finite scores never reach it)
    hipMemsetAsync(ws, 0xFF, (size_t)NN * SS * sizeof(unsigned long long), stream);
    hipMemsetAsync((char*)out + OUT_ELEMS * sizeof(float), 0, sizeof(float), stream);

    // 4096 blocks: [s:5][ksplit:2][ntile:5]
    vq_main<<<dim3((NN / 256) * SS * KSPLIT), dim3(256), 0, stream>>>(z, W, ws);
    // 2048 blocks: [s:5][ntile:6]
    vq_epi<<<dim3((NN / 128) * SS), dim3(256), 0, stream>>>(z, W, ws, out);
}

// Round 8
// 152.488 us; speedup vs baseline: 1.8177x; 1.8177x over previous
//
#include <hip/hip_runtime.h>
#include <math.h>

// Problem constants (fixed by reference setup_inputs)
#define NN 8192
#define SS 32
#define DD 32
#define KK 1024
#define OUT_ELEMS ((size_t)NN * SS * DD)   // 8388608; loss scalar at out[OUT_ELEMS]

// loss = S * (1 + BETA) * sum_sq / (N*S*D)
#define LOSS_SCALE (32.0f * 1.001f / 8388608.0f)

typedef _Float16 half8 __attribute__((ext_vector_type(8)));
typedef float   floatx4 __attribute__((ext_vector_type(4)));

#define CH_TILES 4                    // k-tiles of 16 per chunk
#define CHUNK_K  (CH_TILES * 16)      // 64 codewords per chunk
#define NCHUNK   (KK / CHUNK_K)       // 16 chunks
#define RG 2                          // 16-row groups per wave -> 32 rows/wave
#define NBLOCKS ((NN / 128) * SS)     // 2048 main blocks

// SESSION NOTE (R6 post-mortem): same-address atomicAdd on the loss scalar
// serializes at ~33 cyc each; with all blocks co-resident it is an exposed
// tail (4096 atomics = 56 us, 8192 = 112 us) — it was the hidden floor from
// R1-R6. This version stores per-block partials (distinct addresses, no
// atomics) + a tiny reduce kernel.

// Block = 4 waves, one s per block, 128 n-rows. Grid 2048 = 8 blocks/CU,
// VGPR 44 (measured R5) -> 8 waves/SIMD resident; LDS 17KB*8=136KB<160KB.
__global__ __launch_bounds__(256, 4) void vq_fused(const float* __restrict__ z,
                                                   const float* __restrict__ W,
                                                   float* __restrict__ out,
                                                   float* __restrict__ part) {
    __shared__ _Float16 bufH[2][CH_TILES][64][8];   // 8 KB
    __shared__ _Float16 bufL[2][CH_TILES][64][8];   // 8 KB
    __shared__ float    w2b[2][CHUNK_K];            // 512 B
    __shared__ int      lds_idx[4][32];             // 512 B
    __shared__ float    lds_part[4];

    const int s    = blockIdx.x & (SS - 1);
    const int n0b  = (blockIdx.x >> 5) * 128;
    const int tid  = threadIdx.x;
    const int wv   = tid >> 6;
    const int lane = tid & 63;
    const int col  = lane & 15;
    const int quad = lane >> 4;

    const float* __restrict__ Ws = W + (size_t)s * KK * DD;
    const int n0w = n0b + wv * 32;

    // ---- A-fragments: (-2*z) split into f16 hi/lo. A[m=col][d=quad*8+j]. ----
    half8 zh[RG], zl[RG];
    #pragma unroll
    for (int rg = 0; rg < RG; ++rg) {
        const float* zp = z + (size_t)(n0w + rg * 16 + col) * (SS * DD) + s * DD + quad * 8;
        const float4 va = ((const float4*)zp)[0];
        const float4 vb = ((const float4*)zp)[1];
        const float src[8] = {va.x, va.y, va.z, va.w, vb.x, vb.y, vb.z, vb.w};
        #pragma unroll
        for (int j = 0; j < 8; ++j) {
            const float v = -2.0f * src[j];
            const _Float16 h = (_Float16)v;
            zh[rg][j] = h;
            zl[rg][j] = (_Float16)(v - (float)h);
        }
    }

    // Staging source: thread covers k-row (chunk*64 + wv*16 + col), d=quad*8..+7.
    const float* __restrict__ stg = Ws + ((size_t)(wv * 16 + col)) * DD + quad * 8;

    floatx4 best[RG];
    int bi[RG][4];
    #pragma unroll
    for (int rg = 0; rg < RG; ++rg) {
        best[rg] = (floatx4){INFINITY, INFINITY, INFINITY, INFINITY};
        bi[rg][0] = bi[rg][1] = bi[rg][2] = bi[rg][3] = 0;
    }

    // ---- prologue: stage chunk 0 ----
    float4 pa = ((const float4*)stg)[0];
    float4 pb = ((const float4*)stg)[1];
    {
        const float src[8] = {pa.x, pa.y, pa.z, pa.w, pb.x, pb.y, pb.z, pb.w};
        half8 h8, l8; float ps = 0.0f;
        #pragma unroll
        for (int j = 0; j < 8; ++j) {
            const float v = src[j];
            ps = fmaf(v, v, ps);
            const _Float16 h = (_Float16)v;
            h8[j] = h;
            l8[j] = (_Float16)(v - (float)h);
        }
        ps += __shfl_xor(ps, 16, 64);
        ps += __shfl_xor(ps, 32, 64);
        *(half8*)&bufH[0][wv][lane][0] = h8;
        *(half8*)&bufL[0][wv][lane][0] = l8;
        if (quad == 0) w2b[0][wv * 16 + col] = ps;
    }
    __syncthreads();

    // ---- main K loop, double-buffered ----
    for (int c = 0; c < NCHUNK; ++c) {
        const int b = c & 1;
        if (c + 1 < NCHUNK) {   // issue next chunk's global loads early
            const float* nsrc = stg + (size_t)(c + 1) * CHUNK_K * DD;
            pa = ((const float4*)nsrc)[0];
            pb = ((const float4*)nsrc)[1];
        }

        #pragma unroll
        for (int tt = 0; tt < CH_TILES; ++tt) {
            const half8 bh = *(const half8*)&bufH[b][tt][lane][0];
            const half8 bl = *(const half8*)&bufL[b][tt][lane][0];
            const float wv2 = w2b[b][tt * 16 + col];
            const floatx4 c0 = {wv2, wv2, wv2, wv2};
            const int tk = c * CH_TILES + tt;
            #pragma unroll
            for (int rg = 0; rg < RG; ++rg) {
                floatx4 acc = __builtin_amdgcn_mfma_f32_16x16x32_f16(zh[rg], bh, c0, 0, 0, 0);
                acc = __builtin_amdgcn_mfma_f32_16x16x32_f16(zl[rg], bh, acc, 0, 0, 0);
                acc = __builtin_amdgcn_mfma_f32_16x16x32_f16(zh[rg], bl, acc, 0, 0, 0);
                #pragma unroll
                for (int i = 0; i < 4; ++i) {
                    if (acc[i] < best[rg][i]) { best[rg][i] = acc[i]; bi[rg][i] = tk; }  // strict <
                }
            }
        }

        if (c + 1 < NCHUNK) {
            const float src[8] = {pa.x, pa.y, pa.z, pa.w, pb.x, pb.y, pb.z, pb.w};
            half8 h8, l8; float ps = 0.0f;
            #pragma unroll
            for (int j = 0; j < 8; ++j) {
                const float v = src[j];
                ps = fmaf(v, v, ps);
                const _Float16 h = (_Float16)v;
                h8[j] = h;
                l8[j] = (_Float16)(v - (float)h);
            }
            ps += __shfl_xor(ps, 16, 64);
            ps += __shfl_xor(ps, 32, 64);
            const int nb = (c + 1) & 1;
            *(half8*)&bufH[nb][wv][lane][0] = h8;
            *(half8*)&bufL[nb][wv][lane][0] = l8;
            if (quad == 0) w2b[nb][wv * 16 + col] = ps;
            __syncthreads();
        }
    }

    // ---- cross-lane argmin over the 16 k-columns; lower k wins ties ----
    #pragma unroll
    for (int rg = 0; rg < RG; ++rg) {
        #pragma unroll
        for (int i = 0; i < 4; ++i) {
            float v = best[rg][i];
            int   k = bi[rg][i] * 16 + col;
            #pragma unroll
            for (int m = 1; m < 16; m <<= 1) {
                const float vo = __shfl_xor(v, m, 64);
                const int   ko = __shfl_xor(k, m, 64);
                if (vo < v || (vo == v && ko < k)) { v = vo; k = ko; }
            }
            if (col == 0) lds_idx[wv][rg * 16 + quad * 4 + i] = k;  // row-in-wave
        }
    }
    __syncthreads();

    // ---- epilogue: 2 lanes per n-row (16 floats each); zq = fp32 W[s,k*] ----
    const int r  = lane & 31;
    const int dh = (lane >> 5) * 16;
    const int krow = lds_idx[wv][r];
    const float* wsrc = Ws + (size_t)krow * DD + dh;
    const size_t zoff = (size_t)(n0w + r) * (SS * DD) + s * DD + dh;
    const float* zsrc = z + zoff;
    float* od = out + zoff;
    float sq = 0.0f;
    #pragma unroll
    for (int cc = 0; cc < 4; ++cc) {
        const float4 wq = ((const float4*)wsrc)[cc];
        const float4 zv = ((const float4*)zsrc)[cc];
        const float d0 = wq.x - zv.x, d1 = wq.y - zv.y;
        const float d2 = wq.z - zv.z, d3 = wq.w - zv.w;
        sq = fmaf(d0, d0, sq); sq = fmaf(d1, d1, sq);
        sq = fmaf(d2, d2, sq); sq = fmaf(d3, d3, sq);
        ((float4*)od)[cc] = wq;
    }
    #pragma unroll
    for (int off = 32; off > 0; off >>= 1) sq += __shfl_down(sq, off, 64);

    // per-block partial -> distinct address; NO same-address atomics
    if (lane == 0) lds_part[wv] = sq;
    __syncthreads();
    if (tid == 0)
        part[blockIdx.x] = lds_part[0] + lds_part[1] + lds_part[2] + lds_part[3];
}

// Tiny final reduce: 1 block sums the 2048 per-block partials.
__global__ __launch_bounds__(256) void vq_loss(const float* __restrict__ part,
                                               float* __restrict__ out) {
    __shared__ float l[4];
    const int tid = threadIdx.x;
    float sum = 0.0f;
    #pragma unroll
    for (int i = 0; i < NBLOCKS / 256; ++i) sum += part[tid + i * 256];
    #pragma unroll
    for (int off = 32; off > 0; off >>= 1) sum += __shfl_down(sum, off, 64);
    if ((tid & 63) == 0) l[tid >> 6] = sum;
    __syncthreads();
    if (tid == 0) out[OUT_ELEMS] = (l[0] + l[1] + l[2] + l[3]) * LOSS_SCALE;
}

extern "C" void kernel_launch(void* const* d_in, const int* in_sizes, int n_in,
                              void* d_out, int out_size, void* d_ws, size_t ws_size,
                              hipStream_t stream) {
    const float* z = (const float*)d_in[0];   // (8192, 1024) fp32
    const float* W = (const float*)d_in[1];   // (32, 1024, 32) fp32
    float* out  = (float*)d_out;              // 8388608 zq_st + 1 loss
    float* part = (float*)d_ws;               // NBLOCKS per-block partials (8 KB)

    // 2048 blocks: blockIdx&31 = s, blockIdx>>5 = 128-row n-tile.
    // Every block writes part[blockIdx] unconditionally -> no memset needed.
    vq_fused<<<dim3(NBLOCKS), dim3(256), 0, stream>>>(z, W, out, part);
    vq_loss<<<dim3(1), dim3(256), 0, stream>>>(part, out);
}